// Round 4
// baseline (438.469 us; speedup 1.0000x reference)
//
#include <hip/hip_runtime.h>
#include <hip/hip_bf16.h>

#define H_DIM  1024
#define RANK_  4
#define BATCH_ 128
#define TSTEPS 256
#define M_DIM  (BATCH_ * TSTEPS)   // 32768

typedef __bf16 bf16x8 __attribute__((ext_vector_type(8)));
typedef float  floatx4 __attribute__((ext_vector_type(4)));
typedef unsigned short ushortx8 __attribute__((ext_vector_type(8)));

// RNE float -> bf16 (branchless; inputs are finite)
__device__ __forceinline__ unsigned short f2bf(float f) {
    unsigned u = __float_as_uint(f);
    u += 0x7FFFu + ((u >> 16) & 1u);
    return (unsigned short)(u >> 16);
}

// ---------------- fused conversion kernel ----------------
// blocks [0, NXB): x fp32 -> bf16 (vectorized 8/lane)
// blocks [NXB, NXB+1024): Bt[n][k] = bf16(B[k][n]) 32x32 tiles
#define NXB ((M_DIM * H_DIM) / (256 * 8))   // 16384

__global__ __launch_bounds__(256) void cvt_fused_kernel(const float* __restrict__ x,
                                                        unsigned short* __restrict__ xb,
                                                        const float* __restrict__ B,
                                                        unsigned short* __restrict__ Bt) {
    __shared__ float tl[32][33];
    const int bid = blockIdx.x;
    if (bid < NXB) {
        size_t i = ((size_t)bid * 256 + threadIdx.x) * 8;
        float4 v0 = *(const float4*)(x + i);
        float4 v1 = *(const float4*)(x + i + 4);
        ushortx8 o;
        o[0] = f2bf(v0.x); o[1] = f2bf(v0.y); o[2] = f2bf(v0.z); o[3] = f2bf(v0.w);
        o[4] = f2bf(v1.x); o[5] = f2bf(v1.y); o[6] = f2bf(v1.z); o[7] = f2bf(v1.w);
        *(ushortx8*)(xb + i) = o;
    } else {
        const int t = bid - NXB;               // 0..1023
        int tx = threadIdx.x & 31, ty = threadIdx.x >> 5;   // ty in 0..7
        int k0 = (t >> 5) * 32, n0 = (t & 31) * 32;
#pragma unroll
        for (int j = 0; j < 4; ++j)
            tl[ty + 8 * j][tx] = B[(size_t)(k0 + ty + 8 * j) * H_DIM + n0 + tx];
        __syncthreads();
#pragma unroll
        for (int j = 0; j < 4; ++j)
            Bt[(size_t)(n0 + ty + 8 * j) * H_DIM + k0 + tx] = f2bf(tl[tx][ty + 8 * j]);
    }
}

// ---------------- bf16 MFMA GEMM, 256x256 8-phase schedule ----------------
// (unchanged; inferred ~82us, below the scan on the dispatch table)

#define BM 256
#define BN 256
#define BKK 64
#define KTILES (H_DIM / BKK)   // 16

#define GLD(srcptr, dstptr)                                          \
    __builtin_amdgcn_global_load_lds(                                \
        (const __attribute__((address_space(1))) void*)(srcptr),     \
        (__attribute__((address_space(3))) void*)(dstptr), 16, 0, 0)

#define STAGE_A(buf, hf, kt) do {                                                     \
    GLD(aS0 + (size_t)(hf) * (128 * H_DIM) + (kt) * BKK, &lds[buf][0][hf][dst0]);     \
    GLD(aS1 + (size_t)(hf) * (128 * H_DIM) + (kt) * BKK, &lds[buf][0][hf][dst1]);     \
} while (0)

#define STAGE_B(buf, hf, kt) do {                                                     \
    GLD(bS0 + (size_t)(hf) * (128 * H_DIM) + (kt) * BKK, &lds[buf][1][hf][dst0]);     \
    GLD(bS1 + (size_t)(hf) * (128 * H_DIM) + (kt) * BKK, &lds[buf][1][hf][dst1]);     \
} while (0)

#define MFMA_PHASE(q)                                                                                         \
    _Pragma("unroll")                                                                                         \
    for (int fc = 0; fc < 4; ++fc) {                                                                          \
        acc[2*(q)][fc]   = __builtin_amdgcn_mfma_f32_16x16x32_bf16(a00, bfr[fc][0], acc[2*(q)][fc], 0, 0, 0);   \
        acc[2*(q)][fc]   = __builtin_amdgcn_mfma_f32_16x16x32_bf16(a01, bfr[fc][1], acc[2*(q)][fc], 0, 0, 0);   \
        acc[2*(q)+1][fc] = __builtin_amdgcn_mfma_f32_16x16x32_bf16(a10, bfr[fc][0], acc[2*(q)+1][fc], 0, 0, 0); \
        acc[2*(q)+1][fc] = __builtin_amdgcn_mfma_f32_16x16x32_bf16(a11, bfr[fc][1], acc[2*(q)+1][fc], 0, 0, 0); \
    }

#define PHASE(q, STAGE_STMT, TAIL_STMT) {                                      \
        bf16x8 a00 = *(const bf16x8*)(Ah + (2*(q))     * 1024 + aRow + cs0);   \
        bf16x8 a01 = *(const bf16x8*)(Ah + (2*(q))     * 1024 + aRow + cs1);   \
        bf16x8 a10 = *(const bf16x8*)(Ah + (2*(q) + 1) * 1024 + aRow + cs0);   \
        bf16x8 a11 = *(const bf16x8*)(Ah + (2*(q) + 1) * 1024 + aRow + cs1);   \
        STAGE_STMT;                                                            \
        __builtin_amdgcn_s_barrier();                                          \
        asm volatile("s_waitcnt lgkmcnt(0)" ::: "memory");                     \
        __builtin_amdgcn_s_setprio(1);                                         \
        MFMA_PHASE(q);                                                         \
        __builtin_amdgcn_s_setprio(0);                                         \
        TAIL_STMT;                                                             \
        __builtin_amdgcn_s_barrier();                                          \
    }

__global__ __launch_bounds__(512, 2) void gemm_bf16_256(const unsigned short* __restrict__ A,
                                                        const unsigned short* __restrict__ Bt,
                                                        float* __restrict__ C) {
    __shared__ unsigned short lds[2][2][2][8192];   // [dbuf][A=0/B=1][half][128*64] = 128KB

    const int tid = threadIdx.x;
    const int l   = tid & 63;
    const int w   = tid >> 6;      // 0..7
    const int wr  = w >> 2;        // 0..1  M-side (128 rows)
    const int wc  = w & 3;         // 0..3  N-side (64 cols)

    const int bid = blockIdx.x;
    const int lt  = (bid & 7) * 64 + (bid >> 3);
    const int m0  = (lt >> 2) * BM;
    const int n0  = (lt & 3)  * BN;

    const int p0row = (w * 2 + 0) * 8 + (l >> 3);
    const int p1row = (w * 2 + 1) * 8 + (l >> 3);
    const int gcol  = ((l & 7) ^ (l >> 3)) * 8;
    const int dst0  = (w * 2 + 0) * 512;
    const int dst1  = (w * 2 + 1) * 512;
    const unsigned short* aS0 = A  + (size_t)(m0 + p0row) * H_DIM + gcol;
    const unsigned short* aS1 = A  + (size_t)(m0 + p1row) * H_DIM + gcol;
    const unsigned short* bS0 = Bt + (size_t)(n0 + p0row) * H_DIM + gcol;
    const unsigned short* bS1 = Bt + (size_t)(n0 + p1row) * H_DIM + gcol;

    const int aRow = (l & 15) * 64;
    const int cs0  = (((l >> 4) + 0) ^ (l & 7)) * 8;
    const int cs1  = (((l >> 4) + 4) ^ (l & 7)) * 8;

    floatx4 acc[8][4];
#pragma unroll
    for (int i = 0; i < 8; ++i)
#pragma unroll
        for (int j = 0; j < 4; ++j) acc[i][j] = (floatx4){0.f, 0.f, 0.f, 0.f};

    STAGE_B(0, 0, 0); STAGE_B(0, 1, 0); STAGE_A(0, 0, 0); STAGE_A(0, 1, 0);
    STAGE_B(1, 0, 1); STAGE_B(1, 1, 1); STAGE_A(1, 0, 1);
    asm volatile("s_waitcnt vmcnt(6)" ::: "memory");   // oldest 4 halves (t0) done
    __builtin_amdgcn_s_barrier();

    for (int kt = 0; kt < KTILES; ++kt) {
        const int buf = kt & 1;
        const unsigned short* Ah = &lds[buf][0][wr][0];
        const unsigned short* Bh = &lds[buf][1][wc >> 1][(wc & 1) * 4096];
        bf16x8 bfr[4][2];

        {
            bf16x8 a00 = *(const bf16x8*)(Ah + 0 * 1024 + aRow + cs0);
            bf16x8 a01 = *(const bf16x8*)(Ah + 0 * 1024 + aRow + cs1);
            bf16x8 a10 = *(const bf16x8*)(Ah + 1 * 1024 + aRow + cs0);
            bf16x8 a11 = *(const bf16x8*)(Ah + 1 * 1024 + aRow + cs1);
#pragma unroll
            for (int fc = 0; fc < 4; ++fc) {
                bfr[fc][0] = *(const bf16x8*)(Bh + fc * 1024 + aRow + cs0);
                bfr[fc][1] = *(const bf16x8*)(Bh + fc * 1024 + aRow + cs1);
            }
            if (kt + 1 < KTILES) STAGE_A(buf ^ 1, 1, kt + 1);
            __builtin_amdgcn_s_barrier();
            asm volatile("s_waitcnt lgkmcnt(0)" ::: "memory");
            __builtin_amdgcn_s_setprio(1);
            MFMA_PHASE(0);
            __builtin_amdgcn_s_setprio(0);
            __builtin_amdgcn_s_barrier();
        }
        PHASE(1, if (kt + 2 < KTILES) STAGE_B(buf, 0, kt + 2), );
        PHASE(2, if (kt + 2 < KTILES) STAGE_B(buf, 1, kt + 2), );
        PHASE(3, if (kt + 2 < KTILES) STAGE_A(buf, 0, kt + 2),
              if (kt < KTILES - 2) { asm volatile("s_waitcnt vmcnt(6)" ::: "memory"); }
              else if (kt == KTILES - 2) { asm volatile("s_waitcnt vmcnt(0)" ::: "memory"); });
    }

    const int cr = (l >> 4) * 4;
    const int cc = l & 15;
#pragma unroll
    for (int fr = 0; fr < 8; ++fr)
#pragma unroll
        for (int fc = 0; fc < 4; ++fc) {
            size_t base = (size_t)(m0 + wr * 128 + fr * 16 + cr) * H_DIM
                        + (n0 + wc * 64 + fc * 16 + cc);
#pragma unroll
            for (int r = 0; r < 4; ++r)
                C[base + (size_t)r * H_DIM] = acc[fr][fc][r];
        }
}

// ---------------- fp32 fallback GEMM (only if ws too small) ----------------
__global__ __launch_bounds__(256) void gemm_fp32_fallback(const float* __restrict__ A,
                                                          const float* __restrict__ B,
                                                          float* __restrict__ C) {
    __shared__ float As[64][20];
    __shared__ float Bs[16][68];
    const int tid = threadIdx.x;
    const int bm = blockIdx.x >> 4, bn = blockIdx.x & 15;
    const int m0 = bm * 64, n0 = bn * 64;
    const int tx = (tid & 15) * 4, ty = (tid >> 4) * 4;
    float acc[4][4];
#pragma unroll
    for (int i = 0; i < 4; ++i)
#pragma unroll
        for (int j = 0; j < 4; ++j) acc[i][j] = 0.f;

    for (int kk = 0; kk < H_DIM; kk += 16) {
        float4 av = *(const float4*)(A + (size_t)(m0 + (tid >> 2)) * H_DIM + kk + (tid & 3) * 4);
        float4 bv = *(const float4*)(B + (size_t)(kk + (tid >> 4)) * H_DIM + n0 + (tid & 15) * 4);
        __syncthreads();
        *(float4*)&As[tid >> 2][(tid & 3) * 4] = av;
        *(float4*)&Bs[tid >> 4][(tid & 15) * 4] = bv;
        __syncthreads();
#pragma unroll
        for (int k = 0; k < 16; ++k) {
            float a_[4], b_[4];
#pragma unroll
            for (int i = 0; i < 4; ++i) a_[i] = As[ty + i][k];
#pragma unroll
            for (int j = 0; j < 4; ++j) b_[j] = Bs[k][tx + j];
#pragma unroll
            for (int i = 0; i < 4; ++i)
#pragma unroll
                for (int j = 0; j < 4; ++j) acc[i][j] += a_[i] * b_[j];
        }
    }
#pragma unroll
    for (int i = 0; i < 4; ++i)
#pragma unroll
        for (int j = 0; j < 4; ++j)
            C[(size_t)(m0 + ty + i) * H_DIM + n0 + tx + j] = acc[i][j];
}

// ---------------- sequential scan (in-place on d_out) ----------------
// W=1 structure: ONE wave per batch holds the full H=1024 state (16 els/lane,
// mapped e = q*256 + lane*4 + c for coalesced float4 access). Eliminates the
// cross-wave exchange entirely: no LDS, no barrier, no combine. The wave-sum
// lands in lane 63 (DPP chain) and broadcasts via v_readlane -> SGPR, used
// directly as the 1-SGPR operand of the L*r FMAs. u-ring is depth-2 with
// static indexing (runtime-indexed arrays would spill to scratch).

__device__ __forceinline__ float tanh_fast(float x) {
    float ax = fabsf(x);
    float e  = __expf(-2.0f * ax);
    float t  = (1.0f - e) * __builtin_amdgcn_rcpf(1.0f + e);
    return copysignf(t, x);
}

// DPP wave64 sum: full sum lands in lane 63 (VALU-rate, no LDS/ds_permute).
template <int CTRL, int RMASK>
__device__ __forceinline__ float dpp_add(float x) {
    int v = __builtin_amdgcn_update_dpp(0, __float_as_int(x), CTRL, RMASK, 0xf, true);
    return x + __int_as_float(v);
}
__device__ __forceinline__ float wave_sum64(float x) {
    x = dpp_add<0x111, 0xf>(x);  // row_shr:1
    x = dpp_add<0x112, 0xf>(x);  // row_shr:2
    x = dpp_add<0x114, 0xf>(x);  // row_shr:4
    x = dpp_add<0x118, 0xf>(x);  // row_shr:8  -> lane15 of each row = row sum
    x = dpp_add<0x142, 0xa>(x);  // row_bcast15 -> rows 1,3
    x = dpp_add<0x143, 0xc>(x);  // row_bcast31 -> rows 2,3; lane 63 = total
    return x;
}

#define SCAN_STEP(U, tt) {                                                          \
    float pra[4], prb[4];                                                           \
    _Pragma("unroll")                                                               \
    for (int j = 0; j < 4; ++j) {                                                   \
        pra[j] = Rv[j][0][0] * h[0][0];                                             \
        prb[j] = Rv[j][2][0] * h[2][0];                                             \
        _Pragma("unroll")                                                           \
        for (int c = 1; c < 4; ++c) {                                               \
            pra[j] = fmaf(Rv[j][0][c], h[0][c], pra[j]);                            \
            prb[j] = fmaf(Rv[j][2][c], h[2][c], prb[j]);                            \
        }                                                                           \
        _Pragma("unroll")                                                           \
        for (int c = 0; c < 4; ++c) {                                               \
            pra[j] = fmaf(Rv[j][1][c], h[1][c], pra[j]);                            \
            prb[j] = fmaf(Rv[j][3][c], h[3][c], prb[j]);                            \
        }                                                                           \
    }                                                                               \
    float r[4];                                                                     \
    _Pragma("unroll")                                                               \
    for (int j = 0; j < 4; ++j) {                                                   \
        float s_ = wave_sum64(pra[j] + prb[j]);                                     \
        r[j] = __int_as_float(__builtin_amdgcn_readlane(__float_as_int(s_), 63));   \
    }                                                                               \
    _Pragma("unroll")                                                               \
    for (int q = 0; q < 4; ++q) {                                                   \
        float4 o;                                                                   \
        _Pragma("unroll")                                                           \
        for (int c = 0; c < 4; ++c) {                                               \
            float a = fmaf(dd[q][c], h[q][c], (&U[q].x)[c]);                        \
            a = fmaf(Lv[q][c][0], r[0], a);                                         \
            a = fmaf(Lv[q][c][1], r[1], a);                                         \
            a = fmaf(Lv[q][c][2], r[2], a);                                         \
            a = fmaf(Lv[q][c][3], r[3], a);                                         \
            h[q][c] = tanh_fast(a);                                                 \
            (&o.x)[c] = h[q][c];                                                    \
        }                                                                           \
        *(float4*)(iob + (size_t)(tt) * H_DIM + q * 256) = o;                       \
    }                                                                               \
    if ((tt) + 2 < TSTEPS) {                                                        \
        _Pragma("unroll")                                                           \
        for (int q = 0; q < 4; ++q)                                                 \
            U[q] = *(const float4*)(iob + (size_t)((tt) + 2) * H_DIM + q * 256);    \
    }                                                                               \
}

__global__ __launch_bounds__(64, 1) void scan_kernel(const float* __restrict__ h0,
                                                     const float* __restrict__ d,
                                                     const float* __restrict__ Lm,
                                                     const float* __restrict__ Rm,
                                                     float* __restrict__ io) {
    const int b = blockIdx.x, l = threadIdx.x;   // one wave (64 lanes) per batch

    float h[4][4], dd[4][4], Lv[4][4][4], Rv[4][4][4];
#pragma unroll
    for (int q = 0; q < 4; ++q) {
        float4 hv = *(const float4*)(h0 + (size_t)b * H_DIM + q * 256 + l * 4);
        h[q][0] = hv.x; h[q][1] = hv.y; h[q][2] = hv.z; h[q][3] = hv.w;
        float4 dv = *(const float4*)(d + q * 256 + l * 4);
        dd[q][0] = dv.x; dd[q][1] = dv.y; dd[q][2] = dv.z; dd[q][3] = dv.w;
#pragma unroll
        for (int c = 0; c < 4; ++c) {
            float4 lv = *(const float4*)(Lm + (size_t)(q * 256 + l * 4 + c) * RANK_);
            Lv[q][c][0] = lv.x; Lv[q][c][1] = lv.y; Lv[q][c][2] = lv.z; Lv[q][c][3] = lv.w;
        }
    }
#pragma unroll
    for (int j = 0; j < 4; ++j)
#pragma unroll
        for (int q = 0; q < 4; ++q) {
            float4 rv = *(const float4*)(Rm + (size_t)j * H_DIM + q * 256 + l * 4);
            Rv[j][q][0] = rv.x; Rv[j][q][1] = rv.y; Rv[j][q][2] = rv.z; Rv[j][q][3] = rv.w;
        }

    float* iob = io + (size_t)b * TSTEPS * H_DIM + l * 4;

    // u-ring depth 2, static indexing (u0 = even steps, u1 = odd steps)
    float4 u0[4], u1[4];
#pragma unroll
    for (int q = 0; q < 4; ++q) u0[q] = *(const float4*)(iob + 0 * H_DIM + q * 256);
#pragma unroll
    for (int q = 0; q < 4; ++q) u1[q] = *(const float4*)(iob + 1 * H_DIM + q * 256);

    for (int t = 0; t < TSTEPS; t += 2) {
        SCAN_STEP(u0, t);
        SCAN_STEP(u1, t + 1);
    }
}

// ---------------- launch ----------------

extern "C" void kernel_launch(void* const* d_in, const int* in_sizes, int n_in,
                              void* d_out, int out_size, void* d_ws, size_t ws_size,
                              hipStream_t stream) {
    const float* x  = (const float*)d_in[0];
    const float* h0 = (const float*)d_in[1];
    const float* dd = (const float*)d_in[2];
    const float* L  = (const float*)d_in[3];
    const float* R  = (const float*)d_in[4];
    const float* B  = (const float*)d_in[5];
    float* out = (float*)d_out;

    const size_t need = (size_t)M_DIM * H_DIM * sizeof(unsigned short)
                      + (size_t)H_DIM * H_DIM * sizeof(unsigned short);
    if (ws_size >= need) {
        unsigned short* xb = (unsigned short*)d_ws;
        unsigned short* Bt = xb + (size_t)M_DIM * H_DIM;
        cvt_fused_kernel<<<NXB + 1024, 256, 0, stream>>>(x, xb, B, Bt);
        gemm_bf16_256<<<(M_DIM / BM) * (H_DIM / BN), 512, 0, stream>>>(xb, Bt, out);
    } else {
        gemm_fp32_fallback<<<(M_DIM / 64) * (H_DIM / 64), 256, 0, stream>>>(x, B, out);
    }
    scan_kernel<<<BATCH_, 64, 0, stream>>>(h0, dd, L, R, out);
}